// Round 1
// baseline (3366.730 us; speedup 1.0000x reference)
//
#include <hip/hip_runtime.h>
#include <stdint.h>

// ---------------------------------------------------------------------------
// Problem constants
// ---------------------------------------------------------------------------
#define V_VOCAB 50257
#define V_PAD   50304          // 393 * 128
#define NROWS   8192           // 4 * 2048
#define DIM     512
#define KTOP    10
#define MARGIN  0.3f           // >= 2 * (2^-7 * ||x|| * ||w||) worst case (~0.25)

typedef __attribute__((ext_vector_type(8))) short  short8;
typedef __attribute__((ext_vector_type(4))) float  f32x4;

struct Ctrl { int mc; int namb; int hits; int pad_; };

// ws layout (bytes). Total needed: ~60.24 MB.
#define OFF_WT     0ULL
#define SZ_WT      51511296ULL            // 50304*512*2
#define OFF_XC     (OFF_WT + SZ_WT)
#define SZ_XC      8388608ULL             // 8192*512*2
#define OFF_BPAD   (OFF_XC + SZ_XC)
#define SZ_BPAD    (50304ULL*4)
#define OFF_ROWIDX (OFF_BPAD + SZ_BPAD)
#define OFF_THAT   (OFF_ROWIDX + 32768ULL)
#define OFF_COUNTS (OFF_THAT + 32768ULL)
#define OFF_AMB    (OFF_COUNTS + 32768ULL)
#define OFF_CTRL   (OFF_AMB + 32768ULL)

#define GLOAD16(gp, lp) __builtin_amdgcn_global_load_lds( \
    (const __attribute__((address_space(1))) unsigned int*)(gp), \
    (__attribute__((address_space(3))) unsigned int*)(lp), 16, 0, 0)

__device__ __forceinline__ unsigned short f2bf(float f) {
  unsigned int u = __builtin_bit_cast(unsigned int, f);
  unsigned int r = (u + 0x7FFFu + ((u >> 16) & 1u)) >> 16;   // RNE
  return (unsigned short)r;
}
__device__ __forceinline__ float bf2f(unsigned short h) {
  unsigned int u = ((unsigned int)h) << 16;
  return __builtin_bit_cast(float, u);
}

// ---------------------------------------------------------------------------
// 1. prep: b_pad (pad cols get -1e30 so they never count) + masked-row compaction
// ---------------------------------------------------------------------------
__global__ void k_prep(const int* __restrict__ mask, const float* __restrict__ b,
                       float* __restrict__ bpad, int* __restrict__ rowidx,
                       Ctrl* __restrict__ ctrl) {
  int i = blockIdx.x * 256 + threadIdx.x;
  if (i < V_PAD) bpad[i] = (i < V_VOCAB) ? b[i] : -1e30f;
  if (i < NROWS && mask[i] != 0) {
    int p = atomicAdd(&ctrl->mc, 1);
    rowidx[p] = i;
  }
}

// ---------------------------------------------------------------------------
// 2. transpose+convert: W f32[512][V] -> Wt bf16[V_PAD][512] (row = vocab col)
// ---------------------------------------------------------------------------
__global__ void k_twt(const float* __restrict__ W, unsigned short* __restrict__ Wt) {
  __shared__ float lt[64][65];
  const int vbase = blockIdx.x * 64;
  const int kbase = blockIdx.y * 64;
  const int tid = threadIdx.x;
  // read: 4 k-rows x 64 cols per pass, 16 passes; coalesced along v
  const int krow = tid >> 6;      // 0..3
  const int col  = tid & 63;
  const int v    = vbase + col;
#pragma unroll
  for (int rr = 0; rr < 16; ++rr) {
    int kl = krow + rr * 4;
    float val = (v < V_VOCAB) ? W[(size_t)(kbase + kl) * V_VOCAB + v] : 0.0f;
    lt[kl][col] = val;
  }
  __syncthreads();
  // write: 8 bf16 (16B) per thread per pass, k contiguous
  const int vr = tid >> 3;        // 0..31
  const int kc = tid & 7;         // 0..7 (8 bf16 each)
#pragma unroll
  for (int p = 0; p < 2; ++p) {
    int vl = p * 32 + vr;
    short8 t;
#pragma unroll
    for (int j = 0; j < 8; ++j) t[j] = (short)f2bf(lt[kc * 8 + j][vl]);
    *(short8*)(Wt + (size_t)(vbase + vl) * DIM + kbase + kc * 8) = t;
  }
}

// ---------------------------------------------------------------------------
// 3. convert compacted x rows to bf16 (zero-pad rows >= mc)
// ---------------------------------------------------------------------------
__global__ void k_xc(const float* __restrict__ x, const int* __restrict__ rowidx,
                     const Ctrl* __restrict__ ctrl, unsigned short* __restrict__ Xc) {
  const int wid = threadIdx.x >> 6, lane = threadIdx.x & 63;
  const int i = blockIdx.x * 4 + wid;
  const int mc = ctrl->mc;
  short8 t;
  if (i < mc) {
    const float* src = x + (size_t)rowidx[i] * DIM + lane * 8;
#pragma unroll
    for (int j = 0; j < 8; ++j) t[j] = (short)f2bf(src[j]);
  } else {
#pragma unroll
    for (int j = 0; j < 8; ++j) t[j] = 0;
  }
  *(short8*)(Xc + (size_t)i * DIM + lane * 8) = t;
}

// ---------------------------------------------------------------------------
// 4. per-row approx target score t_hat (bf16 dot, f32 accum; error <= delta)
// ---------------------------------------------------------------------------
__global__ void k_that(const unsigned short* __restrict__ Xc,
                       const unsigned short* __restrict__ Wt,
                       const float* __restrict__ bpad,
                       const int* __restrict__ rowidx, const int* __restrict__ target,
                       const Ctrl* __restrict__ ctrl, float* __restrict__ that) {
  const int wid = threadIdx.x >> 6, lane = threadIdx.x & 63;
  const int i = blockIdx.x * 4 + wid;
  const int mc = ctrl->mc;
  if (i >= mc) { if (lane == 0) that[i] = 1e30f; return; }
  const int tg = target[rowidx[i]];
  short8 xa = *(const short8*)(Xc + (size_t)i * DIM + lane * 8);
  short8 wa = *(const short8*)(Wt + (size_t)tg * DIM + lane * 8);
  float s = 0.f;
#pragma unroll
  for (int j = 0; j < 8; ++j)
    s += bf2f((unsigned short)xa[j]) * bf2f((unsigned short)wa[j]);
#pragma unroll
  for (int d = 1; d < 64; d <<= 1) s += __shfl_xor(s, d, 64);
  if (lane == 0) that[i] = s + bpad[tg];
}

// ---------------------------------------------------------------------------
// 5. fused GEMM-count: 128x128 tile, BK=64, 4 waves (2x2), 16x16x32 bf16 MFMA.
//    XOR slot swizzle (slot ^= row&7) applied on the GLOBAL source so
//    global_load_lds stays linear (m173 pattern); ds_read_b128 un-swizzles.
//    Per row: packed u32 counts  lo = #{s_hat > t_hat - M} (<=V<65536),
//                                hi = #{s_hat > t_hat + M} << 16.
// ---------------------------------------------------------------------------
__launch_bounds__(256, 2)
__global__ void k_count(const unsigned short* __restrict__ Xc,
                        const unsigned short* __restrict__ Wt,
                        const float* __restrict__ bpad, const float* __restrict__ that,
                        const Ctrl* __restrict__ ctrl, unsigned int* __restrict__ counts) {
  const int mc = ctrl->mc;
  const int mbase = blockIdx.y * 128;
  if (mbase >= mc) return;
  const int nbase = blockIdx.x * 128;

  __shared__ unsigned short sA[128 * 64];
  __shared__ unsigned short sB[128 * 64];
  char* sAc = (char*)sA;
  char* sBc = (char*)sB;

  const int tid = threadIdx.x;
  const int w = tid >> 6, lane = tid & 63;
  const int wm = (w >> 1) * 64, wn = (w & 1) * 64;

  // staging geometry: chunk = 1KB = 8 tile-rows of 128B; lane covers 16B
  const int srow = lane >> 3;                 // row within chunk (0..7)
  const int s2   = (lane & 7) ^ srow;         // swizzled source slot

  const char* Ab = (const char*)Xc + (size_t)mbase * 1024;  // row stride 1024B
  const char* Bb = (const char*)Wt + (size_t)nbase * 1024;

  f32x4 acc[4][4];
#pragma unroll
  for (int a = 0; a < 4; ++a)
#pragma unroll
    for (int c = 0; c < 4; ++c) acc[a][c] = (f32x4)0.0f;

  for (int kt = 0; kt < 8; ++kt) {
    const int kk = kt * 128;                  // byte offset of 64-wide k slice
#pragma unroll
    for (int c = 0; c < 4; ++c) {
      const int row  = (w * 4 + c) * 8 + srow;
      const int loff = (w * 4 + c) * 1024 + lane * 16;
      GLOAD16(Ab + (size_t)row * 1024 + kk + s2 * 16, sAc + loff);
      GLOAD16(Bb + (size_t)row * 1024 + kk + s2 * 16, sBc + loff);
    }
    __syncthreads();   // compiler drains vmcnt before barrier
#pragma unroll
    for (int ks = 0; ks < 2; ++ks) {
      short8 af[4], bq[4];
#pragma unroll
      for (int mi = 0; mi < 4; ++mi) {
        const int r  = wm + mi * 16 + (lane & 15);
        const int sl = (ks * 4 + (lane >> 4)) ^ (r & 7);
        af[mi] = *(const short8*)(sAc + r * 128 + sl * 16);
      }
#pragma unroll
      for (int ni = 0; ni < 4; ++ni) {
        const int r  = wn + ni * 16 + (lane & 15);
        const int sl = (ks * 4 + (lane >> 4)) ^ (r & 7);
        bq[ni] = *(const short8*)(sBc + r * 128 + sl * 16);
      }
#pragma unroll
      for (int mi = 0; mi < 4; ++mi)
#pragma unroll
        for (int ni = 0; ni < 4; ++ni)
          acc[mi][ni] = __builtin_amdgcn_mfma_f32_16x16x32_bf16(
              af[mi], bq[ni], acc[mi][ni], 0, 0, 0);
    }
    __syncthreads();
  }

  // epilogue: compare + count; D layout col = lane&15, row = (lane>>4)*4 + reg
  float bv[4];
#pragma unroll
  for (int ni = 0; ni < 4; ++ni)
    bv[ni] = bpad[nbase + wn + ni * 16 + (lane & 15)];

#pragma unroll
  for (int mi = 0; mi < 4; ++mi) {
    unsigned int pc[4];
#pragma unroll
    for (int r = 0; r < 4; ++r) {
      const int m = mbase + wm + mi * 16 + (lane >> 4) * 4 + r;
      const float th  = that[m];
      const float tlo = th - MARGIN, thi = th + MARGIN;
      unsigned int p = 0;
#pragma unroll
      for (int ni = 0; ni < 4; ++ni) {
        const float s = acc[mi][ni][r] + bv[ni];
        p += (s > tlo) ? 1u : 0u;
        p += (s > thi) ? (1u << 16) : 0u;
      }
      pc[r] = p;
    }
#pragma unroll
    for (int r = 0; r < 4; ++r) {
      int p = (int)pc[r];
#pragma unroll
      for (int d = 1; d < 16; d <<= 1) p += __shfl_xor(p, d, 64);
      if ((lane & 15) == 0) {
        const int m = mbase + wm + mi * 16 + (lane >> 4) * 4 + r;
        atomicAdd(&counts[m], (unsigned int)p);
      }
    }
  }
}

// ---------------------------------------------------------------------------
// 6. decide: certain hit / certain miss / ambiguous
// ---------------------------------------------------------------------------
__global__ void k_decide(const unsigned int* __restrict__ counts,
                         Ctrl* __restrict__ ctrl, int* __restrict__ amb) {
  const int i = blockIdx.x * 256 + threadIdx.x;
  if (i >= ctrl->mc) return;
  const unsigned int c = counts[i];
  const unsigned int lo = c & 0xFFFFu, hi = c >> 16;
  if (lo <= KTOP - 1) { atomicAdd(&ctrl->hits, 1); }        // rank <= lo <= 9
  else if (hi >= KTOP) { /* rank >= hi >= 10: miss */ }
  else { int p = atomicAdd(&ctrl->namb, 1); amb[p] = i; }
}

// ---------------------------------------------------------------------------
// 7. fixup: exact f32 rank for ambiguous rows (rare; re-reads W once per row)
// ---------------------------------------------------------------------------
__global__ void k_fix(const float* __restrict__ x, const float* __restrict__ W,
                      const float* __restrict__ b, const int* __restrict__ rowidx,
                      const int* __restrict__ target, const int* __restrict__ amb,
                      Ctrl* __restrict__ ctrl) {
  __shared__ float sx[DIM];
  __shared__ float sst;
  __shared__ int red[256];
  const int namb = ctrl->namb;
  for (int a = blockIdx.x; a < namb; a += gridDim.x) {
    const int i = amb[a];
    const int n = rowidx[i];
    const int tg = target[n];
    sx[threadIdx.x]       = x[(size_t)n * DIM + threadIdx.x];
    sx[threadIdx.x + 256] = x[(size_t)n * DIM + 256 + threadIdx.x];
    __syncthreads();
    if (threadIdx.x == 0) {
      float st = 0.f;
      for (int k = 0; k < DIM; ++k) st = fmaf(sx[k], W[(size_t)k * V_VOCAB + tg], st);
      sst = st + b[tg];
    }
    __syncthreads();
    const float st = sst;
    int cnt = 0;
    for (int j = threadIdx.x; j < V_VOCAB; j += 256) {
      float s = 0.f;
      for (int k = 0; k < DIM; ++k) s = fmaf(sx[k], W[(size_t)k * V_VOCAB + j], s);
      s += b[j];
      cnt += (s > st || (s == st && j < tg)) ? 1 : 0;   // j==tg: identical chain -> equal, not counted
    }
    red[threadIdx.x] = cnt;
    __syncthreads();
    for (int off = 128; off > 0; off >>= 1) {
      if (threadIdx.x < off) red[threadIdx.x] += red[threadIdx.x + off];
      __syncthreads();
    }
    if (threadIdx.x == 0 && red[0] <= KTOP - 1) atomicAdd(&ctrl->hits, 1);
    __syncthreads();
  }
}

// ---------------------------------------------------------------------------
// 8. finalize
// ---------------------------------------------------------------------------
__global__ void k_final(const Ctrl* __restrict__ ctrl, float* __restrict__ out) {
  out[0] = (float)ctrl->hits / (float)ctrl->mc;
}

// ---------------------------------------------------------------------------
extern "C" void kernel_launch(void* const* d_in, const int* in_sizes, int n_in,
                              void* d_out, int out_size, void* d_ws, size_t ws_size,
                              hipStream_t stream) {
  const float* x      = (const float*)d_in[0];   // [8192, 512]
  const int*   target = (const int*)d_in[1];     // [8192]
  const int*   mask   = (const int*)d_in[2];     // [8192]
  const float* W      = (const float*)d_in[3];   // [512, 50257]
  const float* b      = (const float*)d_in[4];   // [50257]
  float* out = (float*)d_out;

  char* ws = (char*)d_ws;
  unsigned short* Wt     = (unsigned short*)(ws + OFF_WT);
  unsigned short* Xc     = (unsigned short*)(ws + OFF_XC);
  float*          bpad   = (float*)(ws + OFF_BPAD);
  int*            rowidx = (int*)(ws + OFF_ROWIDX);
  float*          that   = (float*)(ws + OFF_THAT);
  unsigned int*   counts = (unsigned int*)(ws + OFF_COUNTS);
  int*            amb    = (int*)(ws + OFF_AMB);
  Ctrl*           ctrl   = (Ctrl*)(ws + OFF_CTRL);

  // zero counts + amb + ctrl (contiguous region)
  hipMemsetAsync(ws + OFF_COUNTS, 0, 32768 + 32768 + 16, stream);

  k_prep  <<<197, 256, 0, stream>>>(mask, b, bpad, rowidx, ctrl);
  k_twt   <<<dim3(786, 8), 256, 0, stream>>>(W, Wt);
  k_xc    <<<2048, 256, 0, stream>>>(x, rowidx, ctrl, Xc);
  k_that  <<<2048, 256, 0, stream>>>(Xc, Wt, bpad, rowidx, target, ctrl, that);
  k_count <<<dim3(393, 64), 256, 0, stream>>>(Xc, Wt, bpad, that, ctrl, counts);
  k_decide<<<32, 256, 0, stream>>>(counts, ctrl, amb);
  k_fix   <<<64, 256, 0, stream>>>(x, W, b, rowidx, target, amb, ctrl);
  k_final <<<1, 1, 0, stream>>>(ctrl, out);
}

// Round 2
// 544.062 us; speedup vs baseline: 6.1881x; 6.1881x over previous
//
#include <hip/hip_runtime.h>
#include <stdint.h>

// ---------------------------------------------------------------------------
// Problem constants
// ---------------------------------------------------------------------------
#define V_VOCAB 50257
#define V_PAD   50304          // 393 * 128
#define NROWS   8192           // 4 * 2048
#define DIM     512
#define KTOP    10
#define MARGIN  0.3f           // >= 2 * (2^-7 * ||x|| * ||w||) worst case (~0.25)
#define ACH     8              // amb rows per W-scan pass

typedef __attribute__((ext_vector_type(8))) short  short8;
typedef __attribute__((ext_vector_type(4))) float  f32x4;

struct Ctrl { int mc; int namb; int hits; int pad_; };

// ws layout (bytes). Total needed: ~60.3 MB.
#define OFF_WT     0ULL
#define SZ_WT      51511296ULL            // 50304*512*2
#define OFF_XC     (OFF_WT + SZ_WT)
#define SZ_XC      8388608ULL             // 8192*512*2
#define OFF_BPAD   (OFF_XC + SZ_XC)
#define SZ_BPAD    (50304ULL*4)
#define OFF_ROWIDX (OFF_BPAD + SZ_BPAD)
#define OFF_THAT   (OFF_ROWIDX + 32768ULL)
#define OFF_COUNTS (OFF_THAT + 32768ULL)
#define OFF_AMB    (OFF_COUNTS + 32768ULL)
#define OFF_CTRL   (OFF_AMB + 32768ULL)
#define OFF_RK     (OFF_CTRL + 16ULL)
#define OFF_SST    (OFF_RK + 32768ULL)

#define GLOAD16(gp, lp) __builtin_amdgcn_global_load_lds( \
    (const __attribute__((address_space(1))) unsigned int*)(gp), \
    (__attribute__((address_space(3))) unsigned int*)(lp), 16, 0, 0)

__device__ __forceinline__ unsigned short f2bf(float f) {
  unsigned int u = __builtin_bit_cast(unsigned int, f);
  unsigned int r = (u + 0x7FFFu + ((u >> 16) & 1u)) >> 16;   // RNE
  return (unsigned short)r;
}
__device__ __forceinline__ float bf2f(unsigned short h) {
  unsigned int u = ((unsigned int)h) << 16;
  return __builtin_bit_cast(float, u);
}

// ---------------------------------------------------------------------------
// 1. prep: b_pad (pad cols get -1e30 so they never count) + masked-row compaction
// ---------------------------------------------------------------------------
__global__ void k_prep(const int* __restrict__ mask, const float* __restrict__ b,
                       float* __restrict__ bpad, int* __restrict__ rowidx,
                       Ctrl* __restrict__ ctrl) {
  int i = blockIdx.x * 256 + threadIdx.x;
  if (i < V_PAD) bpad[i] = (i < V_VOCAB) ? b[i] : -1e30f;
  if (i < NROWS && mask[i] != 0) {
    int p = atomicAdd(&ctrl->mc, 1);
    rowidx[p] = i;
  }
}

// ---------------------------------------------------------------------------
// 2. transpose+convert: W f32[512][V] -> Wt bf16[V_PAD][512] (row = vocab col)
// ---------------------------------------------------------------------------
__global__ void k_twt(const float* __restrict__ W, unsigned short* __restrict__ Wt) {
  __shared__ float lt[64][65];
  const int vbase = blockIdx.x * 64;
  const int kbase = blockIdx.y * 64;
  const int tid = threadIdx.x;
  const int krow = tid >> 6;      // 0..3
  const int col  = tid & 63;
  const int v    = vbase + col;
#pragma unroll
  for (int rr = 0; rr < 16; ++rr) {
    int kl = krow + rr * 4;
    float val = (v < V_VOCAB) ? W[(size_t)(kbase + kl) * V_VOCAB + v] : 0.0f;
    lt[kl][col] = val;
  }
  __syncthreads();
  const int vr = tid >> 3;        // 0..31
  const int kc = tid & 7;         // 0..7 (8 bf16 each)
#pragma unroll
  for (int p = 0; p < 2; ++p) {
    int vl = p * 32 + vr;
    short8 t;
#pragma unroll
    for (int j = 0; j < 8; ++j) t[j] = (short)f2bf(lt[kc * 8 + j][vl]);
    *(short8*)(Wt + (size_t)(vbase + vl) * DIM + kbase + kc * 8) = t;
  }
}

// ---------------------------------------------------------------------------
// 3. convert compacted x rows to bf16 (zero-pad rows >= mc)
// ---------------------------------------------------------------------------
__global__ void k_xc(const float* __restrict__ x, const int* __restrict__ rowidx,
                     const Ctrl* __restrict__ ctrl, unsigned short* __restrict__ Xc) {
  const int wid = threadIdx.x >> 6, lane = threadIdx.x & 63;
  const int i = blockIdx.x * 4 + wid;
  const int mc = ctrl->mc;
  short8 t;
  if (i < mc) {
    const float* src = x + (size_t)rowidx[i] * DIM + lane * 8;
#pragma unroll
    for (int j = 0; j < 8; ++j) t[j] = (short)f2bf(src[j]);
  } else {
#pragma unroll
    for (int j = 0; j < 8; ++j) t[j] = 0;
  }
  *(short8*)(Xc + (size_t)i * DIM + lane * 8) = t;
}

// ---------------------------------------------------------------------------
// 4. per-row approx target score t_hat (bf16 dot, f32 accum)
// ---------------------------------------------------------------------------
__global__ void k_that(const unsigned short* __restrict__ Xc,
                       const unsigned short* __restrict__ Wt,
                       const float* __restrict__ bpad,
                       const int* __restrict__ rowidx, const int* __restrict__ target,
                       const Ctrl* __restrict__ ctrl, float* __restrict__ that) {
  const int wid = threadIdx.x >> 6, lane = threadIdx.x & 63;
  const int i = blockIdx.x * 4 + wid;
  const int mc = ctrl->mc;
  if (i >= mc) { if (lane == 0) that[i] = 1e30f; return; }
  const int tg = target[rowidx[i]];
  short8 xa = *(const short8*)(Xc + (size_t)i * DIM + lane * 8);
  short8 wa = *(const short8*)(Wt + (size_t)tg * DIM + lane * 8);
  float s = 0.f;
#pragma unroll
  for (int j = 0; j < 8; ++j)
    s += bf2f((unsigned short)xa[j]) * bf2f((unsigned short)wa[j]);
#pragma unroll
  for (int d = 1; d < 64; d <<= 1) s += __shfl_xor(s, d, 64);
  if (lane == 0) that[i] = s + bpad[tg];
}

// ---------------------------------------------------------------------------
// 5. fused GEMM-count: 128x128 tile, BK=64, 4 waves (2x2), 16x16x32 bf16 MFMA.
//    XOR slot swizzle applied on the GLOBAL source (m173 pattern).
//    Per row packed u32: lo = #{s_hat > t_hat - M}, hi = #{s_hat > t_hat + M}<<16
// ---------------------------------------------------------------------------
__launch_bounds__(256, 2)
__global__ void k_count(const unsigned short* __restrict__ Xc,
                        const unsigned short* __restrict__ Wt,
                        const float* __restrict__ bpad, const float* __restrict__ that,
                        const Ctrl* __restrict__ ctrl, unsigned int* __restrict__ counts) {
  const int mc = ctrl->mc;
  const int mbase = blockIdx.y * 128;
  if (mbase >= mc) return;
  const int nbase = blockIdx.x * 128;

  __shared__ unsigned short sA[128 * 64];
  __shared__ unsigned short sB[128 * 64];
  char* sAc = (char*)sA;
  char* sBc = (char*)sB;

  const int tid = threadIdx.x;
  const int w = tid >> 6, lane = tid & 63;
  const int wm = (w >> 1) * 64, wn = (w & 1) * 64;

  const int srow = lane >> 3;                 // row within 1KB chunk (0..7)
  const int s2   = (lane & 7) ^ srow;         // swizzled source slot

  const char* Ab = (const char*)Xc + (size_t)mbase * 1024;
  const char* Bb = (const char*)Wt + (size_t)nbase * 1024;

  f32x4 acc[4][4];
#pragma unroll
  for (int a = 0; a < 4; ++a)
#pragma unroll
    for (int c = 0; c < 4; ++c) acc[a][c] = (f32x4)0.0f;

  for (int kt = 0; kt < 8; ++kt) {
    const int kk = kt * 128;
#pragma unroll
    for (int c = 0; c < 4; ++c) {
      const int row  = (w * 4 + c) * 8 + srow;
      const int loff = (w * 4 + c) * 1024 + lane * 16;
      GLOAD16(Ab + (size_t)row * 1024 + kk + s2 * 16, sAc + loff);
      GLOAD16(Bb + (size_t)row * 1024 + kk + s2 * 16, sBc + loff);
    }
    __syncthreads();
#pragma unroll
    for (int ks = 0; ks < 2; ++ks) {
      short8 af[4], bq[4];
#pragma unroll
      for (int mi = 0; mi < 4; ++mi) {
        const int r  = wm + mi * 16 + (lane & 15);
        const int sl = (ks * 4 + (lane >> 4)) ^ (r & 7);
        af[mi] = *(const short8*)(sAc + r * 128 + sl * 16);
      }
#pragma unroll
      for (int ni = 0; ni < 4; ++ni) {
        const int r  = wn + ni * 16 + (lane & 15);
        const int sl = (ks * 4 + (lane >> 4)) ^ (r & 7);
        bq[ni] = *(const short8*)(sBc + r * 128 + sl * 16);
      }
#pragma unroll
      for (int mi = 0; mi < 4; ++mi)
#pragma unroll
        for (int ni = 0; ni < 4; ++ni)
          acc[mi][ni] = __builtin_amdgcn_mfma_f32_16x16x32_bf16(
              af[mi], bq[ni], acc[mi][ni], 0, 0, 0);
    }
    __syncthreads();
  }

  float bv[4];
#pragma unroll
  for (int ni = 0; ni < 4; ++ni)
    bv[ni] = bpad[nbase + wn + ni * 16 + (lane & 15)];

#pragma unroll
  for (int mi = 0; mi < 4; ++mi) {
    unsigned int pc[4];
#pragma unroll
    for (int r = 0; r < 4; ++r) {
      const int m = mbase + wm + mi * 16 + (lane >> 4) * 4 + r;
      const float th  = that[m];
      const float tlo = th - MARGIN, thi = th + MARGIN;
      unsigned int p = 0;
#pragma unroll
      for (int ni = 0; ni < 4; ++ni) {
        const float s = acc[mi][ni][r] + bv[ni];
        p += (s > tlo) ? 1u : 0u;
        p += (s > thi) ? (1u << 16) : 0u;
      }
      pc[r] = p;
    }
#pragma unroll
    for (int r = 0; r < 4; ++r) {
      int p = (int)pc[r];
#pragma unroll
      for (int d = 1; d < 16; d <<= 1) p += __shfl_xor(p, d, 64);
      if ((lane & 15) == 0) {
        const int m = mbase + wm + mi * 16 + (lane >> 4) * 4 + r;
        atomicAdd(&counts[m], (unsigned int)p);
      }
    }
  }
}

// ---------------------------------------------------------------------------
// 6. decide: certain hit / certain miss / ambiguous
// ---------------------------------------------------------------------------
__global__ void k_decide(const unsigned int* __restrict__ counts,
                         Ctrl* __restrict__ ctrl, int* __restrict__ amb) {
  const int i = blockIdx.x * 256 + threadIdx.x;
  if (i >= ctrl->mc) return;
  const unsigned int c = counts[i];
  const unsigned int lo = c & 0xFFFFu, hi = c >> 16;
  if (lo <= KTOP - 1) { atomicAdd(&ctrl->hits, 1); }
  else if (hi >= KTOP) { /* certain miss */ }
  else { int p = atomicAdd(&ctrl->namb, 1); amb[p] = i; }
}

// ---------------------------------------------------------------------------
// 7a. fixup targets: exact f32 target score, sequential-k fmaf chain.
//     MUST match k_fixscan's chain bitwise (same order, same fmaf, +b last).
// ---------------------------------------------------------------------------
__global__ void k_fixt(const float* __restrict__ x, const float* __restrict__ W,
                       const float* __restrict__ b, const int* __restrict__ rowidx,
                       const int* __restrict__ target, const int* __restrict__ amb,
                       const Ctrl* __restrict__ ctrl, float* __restrict__ sst) {
  const int a = blockIdx.x * 64 + threadIdx.x;
  if (a >= ctrl->namb) return;
  const int n = rowidx[amb[a]];
  const int tg = target[n];
  float st = 0.f;
  for (int k = 0; k < DIM; ++k)
    st = fmaf(x[(size_t)n * DIM + k], W[(size_t)k * V_VOCAB + tg], st);
  sst[a] = st + b[tg];
}

// ---------------------------------------------------------------------------
// 7b. fixup scan: ONE coalesced streaming pass over W (natural [k][j] layout)
//     for up to ACH amb rows at a time. Each thread owns one vocab column j,
//     accumulates ACH dot products with x rows broadcast from LDS.
//     Exact-rank semantics identical to round-1 kernel (same fmaf chain).
// ---------------------------------------------------------------------------
__global__ void k_fixscan(const float* __restrict__ x, const float* __restrict__ W,
                          const float* __restrict__ b, const int* __restrict__ rowidx,
                          const int* __restrict__ target, const int* __restrict__ amb,
                          const float* __restrict__ sst, const Ctrl* __restrict__ ctrl,
                          int* __restrict__ rk) {
  __shared__ float sx[ACH][DIM];
  const int j = blockIdx.x * 256 + threadIdx.x;
  const int namb = ctrl->namb;
  const float bj = (j < V_VOCAB) ? b[j] : 0.f;
  for (int base = 0; base < namb; base += ACH) {
    __syncthreads();
    for (int t = threadIdx.x; t < ACH * DIM / 4; t += 256) {
      const int a  = t / (DIM / 4);
      const int kk = (t % (DIM / 4)) * 4;
      f32x4 v = (f32x4)0.f;
      if (base + a < namb) {
        const int n = rowidx[amb[base + a]];
        v = *(const f32x4*)(x + (size_t)n * DIM + kk);
      }
      *(f32x4*)(&sx[a][kk]) = v;
    }
    __syncthreads();
    if (j >= V_VOCAB) continue;
    float s[ACH];
#pragma unroll
    for (int a = 0; a < ACH; ++a) s[a] = 0.f;
    for (int k = 0; k < DIM; ++k) {
      const float wv = W[(size_t)k * V_VOCAB + j];
#pragma unroll
      for (int a = 0; a < ACH; ++a) s[a] = fmaf(sx[a][k], wv, s[a]);
    }
#pragma unroll
    for (int a = 0; a < ACH; ++a) {
      if (base + a < namb) {
        const int tg = target[rowidx[amb[base + a]]];
        const float sc = s[a] + bj;
        const float st = sst[base + a];
        if (sc > st || (sc == st && j < tg)) atomicAdd(&rk[base + a], 1);
      }
    }
  }
}

// ---------------------------------------------------------------------------
// 7c. fixup decide
// ---------------------------------------------------------------------------
__global__ void k_fixdec(const int* __restrict__ rk, Ctrl* __restrict__ ctrl) {
  const int a = blockIdx.x * 256 + threadIdx.x;
  if (a < ctrl->namb && rk[a] <= KTOP - 1) atomicAdd(&ctrl->hits, 1);
}

// ---------------------------------------------------------------------------
// 8. finalize
// ---------------------------------------------------------------------------
__global__ void k_final(const Ctrl* __restrict__ ctrl, float* __restrict__ out) {
  out[0] = (float)ctrl->hits / (float)ctrl->mc;
}

// ---------------------------------------------------------------------------
extern "C" void kernel_launch(void* const* d_in, const int* in_sizes, int n_in,
                              void* d_out, int out_size, void* d_ws, size_t ws_size,
                              hipStream_t stream) {
  const float* x      = (const float*)d_in[0];   // [8192, 512]
  const int*   target = (const int*)d_in[1];     // [8192]
  const int*   mask   = (const int*)d_in[2];     // [8192]
  const float* W      = (const float*)d_in[3];   // [512, 50257]
  const float* b      = (const float*)d_in[4];   // [50257]
  float* out = (float*)d_out;

  char* ws = (char*)d_ws;
  unsigned short* Wt     = (unsigned short*)(ws + OFF_WT);
  unsigned short* Xc     = (unsigned short*)(ws + OFF_XC);
  float*          bpad   = (float*)(ws + OFF_BPAD);
  int*            rowidx = (int*)(ws + OFF_ROWIDX);
  float*          that   = (float*)(ws + OFF_THAT);
  unsigned int*   counts = (unsigned int*)(ws + OFF_COUNTS);
  int*            amb    = (int*)(ws + OFF_AMB);
  Ctrl*           ctrl   = (Ctrl*)(ws + OFF_CTRL);
  int*            rk     = (int*)(ws + OFF_RK);
  float*          sst    = (float*)(ws + OFF_SST);

  // zero counts + amb + ctrl + rk (contiguous region)
  hipMemsetAsync(ws + OFF_COUNTS, 0, 32768 + 32768 + 16 + 32768, stream);

  k_prep   <<<197, 256, 0, stream>>>(mask, b, bpad, rowidx, ctrl);
  k_twt    <<<dim3(786, 8), 256, 0, stream>>>(W, Wt);
  k_xc     <<<2048, 256, 0, stream>>>(x, rowidx, ctrl, Xc);
  k_that   <<<2048, 256, 0, stream>>>(Xc, Wt, bpad, rowidx, target, ctrl, that);
  k_count  <<<dim3(393, 64), 256, 0, stream>>>(Xc, Wt, bpad, that, ctrl, counts);
  k_decide <<<32, 256, 0, stream>>>(counts, ctrl, amb);
  k_fixt   <<<128, 64, 0, stream>>>(x, W, b, rowidx, target, amb, ctrl, sst);
  k_fixscan<<<197, 256, 0, stream>>>(x, W, b, rowidx, target, amb, sst, ctrl, rk);
  k_fixdec <<<32, 256, 0, stream>>>(rk, ctrl);
  k_final  <<<1, 1, 0, stream>>>(ctrl, out);
}

// Round 3
// 518.078 us; speedup vs baseline: 6.4985x; 1.0502x over previous
//
#include <hip/hip_runtime.h>
#include <stdint.h>

// ---------------------------------------------------------------------------
// Problem constants
// ---------------------------------------------------------------------------
#define V_VOCAB 50257
#define V_PAD   50432          // 197 * 256
#define NT_N    197            // N tiles of 256
#define NROWS   8192           // 4 * 2048
#define DIM     512
#define KTOP    10
#define MARGIN  0.3f           // >= 2 * (2^-7 * ||x|| * ||w||) worst case (~0.25)
#define ACH     8              // amb rows per W-scan pass

typedef __attribute__((ext_vector_type(8))) short  short8;
typedef __attribute__((ext_vector_type(4))) float  f32x4;

struct Ctrl { int mc; int namb; int hits; int pad_; };

// ws layout (bytes). Total ~60.4 MB.
#define OFF_WT     0ULL
#define SZ_WT      51642368ULL            // 50432*512*2
#define OFF_XC     (OFF_WT + SZ_WT)
#define SZ_XC      8388608ULL             // 8192*512*2
#define OFF_BPAD   (OFF_XC + SZ_XC)
#define SZ_BPAD    (50432ULL*4)
#define OFF_ROWIDX (OFF_BPAD + SZ_BPAD)
#define OFF_THAT   (OFF_ROWIDX + 32768ULL)
#define OFF_COUNTS (OFF_THAT + 32768ULL)
#define OFF_AMB    (OFF_COUNTS + 32768ULL)
#define OFF_CTRL   (OFF_AMB + 32768ULL)
#define OFF_RK     (OFF_CTRL + 16ULL)
#define OFF_SST    (OFF_RK + 32768ULL)

#define GLOAD16(gp, lp) __builtin_amdgcn_global_load_lds( \
    (const __attribute__((address_space(1))) unsigned int*)(gp), \
    (__attribute__((address_space(3))) unsigned int*)(lp), 16, 0, 0)

#define SBAR()  do { asm volatile("" ::: "memory"); __builtin_amdgcn_s_barrier(); \
                     asm volatile("" ::: "memory"); } while (0)
#define LGKM0() asm volatile("s_waitcnt lgkmcnt(0)" ::: "memory")
#define VM2()   asm volatile("s_waitcnt vmcnt(2)" ::: "memory")
#define VM0()   asm volatile("s_waitcnt vmcnt(0)" ::: "memory")

__device__ __forceinline__ unsigned short f2bf(float f) {
  unsigned int u = __builtin_bit_cast(unsigned int, f);
  unsigned int r = (u + 0x7FFFu + ((u >> 16) & 1u)) >> 16;   // RNE
  return (unsigned short)r;
}
__device__ __forceinline__ float bf2f(unsigned short h) {
  unsigned int u = ((unsigned int)h) << 16;
  return __builtin_bit_cast(float, u);
}

// ---------------------------------------------------------------------------
// 1. prep
// ---------------------------------------------------------------------------
__global__ void k_prep(const int* __restrict__ mask, const float* __restrict__ b,
                       float* __restrict__ bpad, int* __restrict__ rowidx,
                       Ctrl* __restrict__ ctrl) {
  int i = blockIdx.x * 256 + threadIdx.x;
  if (i < V_PAD) bpad[i] = (i < V_VOCAB) ? b[i] : -1e30f;
  if (i < NROWS && mask[i] != 0) {
    int p = atomicAdd(&ctrl->mc, 1);
    rowidx[p] = i;
  }
}

// ---------------------------------------------------------------------------
// 2. transpose+convert: W f32[512][V] -> Wt bf16[V_PAD][512]
// ---------------------------------------------------------------------------
__global__ void k_twt(const float* __restrict__ W, unsigned short* __restrict__ Wt) {
  __shared__ float lt[64][65];
  const int vbase = blockIdx.x * 64;
  const int kbase = blockIdx.y * 64;
  const int tid = threadIdx.x;
  const int krow = tid >> 6;
  const int col  = tid & 63;
  const int v    = vbase + col;
#pragma unroll
  for (int rr = 0; rr < 16; ++rr) {
    int kl = krow + rr * 4;
    float val = (v < V_VOCAB) ? W[(size_t)(kbase + kl) * V_VOCAB + v] : 0.0f;
    lt[kl][col] = val;
  }
  __syncthreads();
  const int vr = tid >> 3;
  const int kc = tid & 7;
#pragma unroll
  for (int p = 0; p < 2; ++p) {
    int vl = p * 32 + vr;
    short8 t;
#pragma unroll
    for (int j = 0; j < 8; ++j) t[j] = (short)f2bf(lt[kc * 8 + j][vl]);
    *(short8*)(Wt + (size_t)(vbase + vl) * DIM + kbase + kc * 8) = t;
  }
}

// ---------------------------------------------------------------------------
// 3. convert compacted x rows to bf16
// ---------------------------------------------------------------------------
__global__ void k_xc(const float* __restrict__ x, const int* __restrict__ rowidx,
                     const Ctrl* __restrict__ ctrl, unsigned short* __restrict__ Xc) {
  const int wid = threadIdx.x >> 6, lane = threadIdx.x & 63;
  const int i = blockIdx.x * 4 + wid;
  const int mc = ctrl->mc;
  short8 t;
  if (i < mc) {
    const float* src = x + (size_t)rowidx[i] * DIM + lane * 8;
#pragma unroll
    for (int j = 0; j < 8; ++j) t[j] = (short)f2bf(src[j]);
  } else {
#pragma unroll
    for (int j = 0; j < 8; ++j) t[j] = 0;
  }
  *(short8*)(Xc + (size_t)i * DIM + lane * 8) = t;
}

// ---------------------------------------------------------------------------
// 4. per-row approx target score t_hat
// ---------------------------------------------------------------------------
__global__ void k_that(const unsigned short* __restrict__ Xc,
                       const unsigned short* __restrict__ Wt,
                       const float* __restrict__ bpad,
                       const int* __restrict__ rowidx, const int* __restrict__ target,
                       const Ctrl* __restrict__ ctrl, float* __restrict__ that) {
  const int wid = threadIdx.x >> 6, lane = threadIdx.x & 63;
  const int i = blockIdx.x * 4 + wid;
  const int mc = ctrl->mc;
  if (i >= mc) { if (lane == 0) that[i] = 1e30f; return; }
  const int tg = target[rowidx[i]];
  short8 xa = *(const short8*)(Xc + (size_t)i * DIM + lane * 8);
  short8 wa = *(const short8*)(Wt + (size_t)tg * DIM + lane * 8);
  float s = 0.f;
#pragma unroll
  for (int j = 0; j < 8; ++j)
    s += bf2f((unsigned short)xa[j]) * bf2f((unsigned short)wa[j]);
#pragma unroll
  for (int d = 1; d < 64; d <<= 1) s += __shfl_xor(s, d, 64);
  if (lane == 0) that[i] = s + bpad[tg];
}

// ---------------------------------------------------------------------------
// 5. fused GEMM-count, 256x256 8-phase (T1+T2+T3+T4+T5).
//    8 waves (2M x 4N), BK=64, dbuf LDS 128KB, XOR slot swizzle via
//    pre-swizzled global source (linear gload_lds dest), counted vmcnt(2)
//    once per K-tile (phases 3 and 7), setprio around MFMA clusters.
//    Stage schedule (steady state, iter i computes K-tiles 2i[buf0] 2i+1[buf1]):
//      p0: b1.Bh1(2i+1)  p1: b1.Ah0(2i+1)  p2: b1.Ah1(2i+1)  p3: b0.Bh0(2i+2)
//      p4: b0.Bh1(2i+2)  p5: b0.Ah0(2i+2)  p6: b0.Ah1(2i+2)  p7: b1.Bh0(2i+3)
//    Each stage targets regions whose last ds_read completed >=1 barrier ago.
// ---------------------------------------------------------------------------
__launch_bounds__(512, 2)
__global__ void k_count(const unsigned short* __restrict__ Xc,
                        const unsigned short* __restrict__ Wt,
                        const float* __restrict__ bpad, const float* __restrict__ that,
                        const Ctrl* __restrict__ ctrl, unsigned int* __restrict__ counts) {
  const int mc = ctrl->mc;
  // bijective XCD swizzle: 6304 blocks, 6304%8==0, M innermost per XCD
  const int lin = blockIdx.y * NT_N + blockIdx.x;
  const int wg  = (lin & 7) * 788 + (lin >> 3);
  const int mt = wg & 31;
  const int nt = wg >> 5;
  const int mbase = mt * 256;
  if (mbase >= mc) return;
  const int nbase = nt * 256;

  __shared__ char lds[131072];   // A: buf q at q*32768; B: 65536 + q*32768

  const int tid  = threadIdx.x;
  const int lane = tid & 63;
  const int w    = tid >> 6;
  const int wr   = w >> 2;          // 0..1
  const int wc   = w & 3;           // 0..3

  const char* Ag = (const char*)Xc + (size_t)mbase * 1024;   // row stride 1024B
  const char* Bg = (const char*)Wt + (size_t)nbase * 1024;
  const int s2 = (tid & 7) ^ ((tid >> 3) & 7);               // swizzled src slot
  const size_t gsrc_off = (size_t)(tid >> 3) * 1024 + (size_t)s2 * 16;
  const int    ldst_off = (tid >> 3) * 128 + (tid & 7) * 16;

  // stage one half-tile (128 rows x 64 k): 2 x global_load_lds dwordx4
#define STAGE_HALF(isA, q, h, ktb) do {                                        \
    const char* _g = ((isA) ? Ag : Bg) + (size_t)(h) * 131072 + (size_t)(ktb) + gsrc_off; \
    char* _l = lds + ((isA) ? 0 : 65536) + (q) * 32768 + (h) * 16384 + ldst_off; \
    GLOAD16(_g, _l);                                                           \
    GLOAD16(_g + 65536, _l + 8192);                                            \
  } while (0)

  const int fr = lane & 15;
  const int fq = lane >> 4;
  const int sl0 = (fq)     ^ (lane & 7);    // phys slot for logical ks0 slot
  const int sl1 = (4 + fq) ^ (lane & 7);    // ks1

#define LDA4(q, ks, mh) do {                                                   \
    const char* _b = lds + (q) * 32768;                                        \
    const int _sl = (ks) ? sl1 : sl0;                                          \
    _Pragma("unroll") for (int _j = 0; _j < 4; ++_j) {                         \
      const int _r = wr * 128 + (mh) * 64 + _j * 16 + fr;                      \
      af[_j] = *(const short8*)(_b + _r * 128 + _sl * 16); }                   \
  } while (0)
#define LDB4(q, ks) do {                                                       \
    const char* _b = lds + 65536 + (q) * 32768;                                \
    const int _sl = (ks) ? sl1 : sl0;                                          \
    _Pragma("unroll") for (int _j = 0; _j < 4; ++_j) {                         \
      const int _r = wc * 64 + _j * 16 + fr;                                   \
      bf[_j] = *(const short8*)(_b + _r * 128 + _sl * 16); }                   \
  } while (0)
#define MFMA16(mh) do {                                                        \
    __builtin_amdgcn_s_setprio(1);                                             \
    _Pragma("unroll") for (int _m = 0; _m < 4; ++_m)                           \
    _Pragma("unroll") for (int _n = 0; _n < 4; ++_n)                           \
      acc[(mh) * 4 + _m][_n] = __builtin_amdgcn_mfma_f32_16x16x32_bf16(        \
          af[_m], bf[_n], acc[(mh) * 4 + _m][_n], 0, 0, 0);                    \
    __builtin_amdgcn_s_setprio(0);                                             \
  } while (0)

  f32x4 acc[8][4];
#pragma unroll
  for (int a = 0; a < 8; ++a)
#pragma unroll
    for (int c = 0; c < 4; ++c) acc[a][c] = (f32x4)0.0f;

  short8 af[4], bf[4];

  // prologue: buf0 <- K-tile 0 (4 halves), buf1.Bh0 <- K-tile 1
  STAGE_HALF(0, 0, 0, 0);   STAGE_HALF(0, 0, 1, 0);
  STAGE_HALF(1, 0, 0, 0);   STAGE_HALF(1, 0, 1, 0);
  STAGE_HALF(0, 1, 0, 128);
  VM2(); SBAR();

#pragma unroll
  for (int i = 0; i < 4; ++i) {
    const int ktn  = (2 * i + 1) * 128;                       // buf1, this iter
    const int ktp2 = (2 * i + 2 < 8 ? 2 * i + 2 : 0) * 128;   // buf0 refill (clamped)
    const int ktp3 = (2 * i + 3 < 8 ? 2 * i + 3 : 0) * 128;   // buf1 refill (clamped)
    // p0: buf0 ks0 mh0
    LDB4(0, 0); LDA4(0, 0, 0);
    STAGE_HALF(0, 1, 1, ktn);
    SBAR(); LGKM0(); MFMA16(0); SBAR();
    // p1: buf0 ks0 mh1
    LDA4(0, 0, 1);
    STAGE_HALF(1, 1, 0, ktn);
    SBAR(); LGKM0(); MFMA16(1); SBAR();
    // p2: buf0 ks1 mh0
    LDB4(0, 1); LDA4(0, 1, 0);
    STAGE_HALF(1, 1, 1, ktn);
    SBAR(); LGKM0(); MFMA16(0); SBAR();
    // p3: buf0 ks1 mh1
    LDA4(0, 1, 1);
    STAGE_HALF(0, 0, 0, ktp2);
    SBAR(); LGKM0(); MFMA16(1);
    VM2(); SBAR();
    // p4: buf1 ks0 mh0
    LDB4(1, 0); LDA4(1, 0, 0);
    STAGE_HALF(0, 0, 1, ktp2);
    SBAR(); LGKM0(); MFMA16(0); SBAR();
    // p5: buf1 ks0 mh1
    LDA4(1, 0, 1);
    STAGE_HALF(1, 0, 0, ktp2);
    SBAR(); LGKM0(); MFMA16(1); SBAR();
    // p6: buf1 ks1 mh0
    LDB4(1, 1); LDA4(1, 1, 0);
    STAGE_HALF(1, 0, 1, ktp2);
    SBAR(); LGKM0(); MFMA16(0); SBAR();
    // p7: buf1 ks1 mh1
    LDA4(1, 1, 1);
    STAGE_HALF(0, 1, 0, ktp3);
    SBAR(); LGKM0(); MFMA16(1);
    VM2(); SBAR();
  }
  VM0();   // drain tail prefetches (never consumed)

  // epilogue: compare + count. D frag: col = lane&15, row = fq*4 + reg
  float bv[4];
#pragma unroll
  for (int ni = 0; ni < 4; ++ni)
    bv[ni] = bpad[nbase + wc * 64 + ni * 16 + fr];

#pragma unroll
  for (int mi = 0; mi < 8; ++mi) {
#pragma unroll
    for (int r = 0; r < 4; ++r) {
      const int m = mbase + wr * 128 + mi * 16 + fq * 4 + r;
      const float th  = that[m];
      const float tlo = th - MARGIN, thi = th + MARGIN;
      unsigned int p = 0;
#pragma unroll
      for (int ni = 0; ni < 4; ++ni) {
        const float s = acc[mi][ni][r] + bv[ni];
        p += (s > tlo) ? 1u : 0u;
        p += (s > thi) ? (1u << 16) : 0u;
      }
      int pi = (int)p;
#pragma unroll
      for (int d = 1; d < 16; d <<= 1) pi += __shfl_xor(pi, d, 64);
      if ((lane & 15) == 0) atomicAdd(&counts[m], (unsigned int)pi);
    }
  }
#undef STAGE_HALF
#undef LDA4
#undef LDB4
#undef MFMA16
}

// ---------------------------------------------------------------------------
// 6. decide
// ---------------------------------------------------------------------------
__global__ void k_decide(const unsigned int* __restrict__ counts,
                         Ctrl* __restrict__ ctrl, int* __restrict__ amb) {
  const int i = blockIdx.x * 256 + threadIdx.x;
  if (i >= ctrl->mc) return;
  const unsigned int c = counts[i];
  const unsigned int lo = c & 0xFFFFu, hi = c >> 16;
  if (lo <= KTOP - 1) { atomicAdd(&ctrl->hits, 1); }
  else if (hi >= KTOP) { /* certain miss */ }
  else { int p = atomicAdd(&ctrl->namb, 1); amb[p] = i; }
}

// ---------------------------------------------------------------------------
// 7a. fixup targets (exact f32, sequential fmaf chain — must match k_fixscan)
// ---------------------------------------------------------------------------
__global__ void k_fixt(const float* __restrict__ x, const float* __restrict__ W,
                       const float* __restrict__ b, const int* __restrict__ rowidx,
                       const int* __restrict__ target, const int* __restrict__ amb,
                       const Ctrl* __restrict__ ctrl, float* __restrict__ sst) {
  const int a = blockIdx.x * 64 + threadIdx.x;
  if (a >= ctrl->namb) return;
  const int n = rowidx[amb[a]];
  const int tg = target[n];
  float st = 0.f;
  for (int k = 0; k < DIM; ++k)
    st = fmaf(x[(size_t)n * DIM + k], W[(size_t)k * V_VOCAB + tg], st);
  sst[a] = st + b[tg];
}

// ---------------------------------------------------------------------------
// 7b. fixup scan: one coalesced streaming pass over W for <=ACH rows at a time
// ---------------------------------------------------------------------------
__global__ void k_fixscan(const float* __restrict__ x, const float* __restrict__ W,
                          const float* __restrict__ b, const int* __restrict__ rowidx,
                          const int* __restrict__ target, const int* __restrict__ amb,
                          const float* __restrict__ sst, const Ctrl* __restrict__ ctrl,
                          int* __restrict__ rk) {
  __shared__ float sx[ACH][DIM];
  const int j = blockIdx.x * 256 + threadIdx.x;
  const int namb = ctrl->namb;
  const float bj = (j < V_VOCAB) ? b[j] : 0.f;
  for (int base = 0; base < namb; base += ACH) {
    __syncthreads();
    for (int t = threadIdx.x; t < ACH * DIM / 4; t += 256) {
      const int a  = t / (DIM / 4);
      const int kk = (t % (DIM / 4)) * 4;
      f32x4 v = (f32x4)0.f;
      if (base + a < namb) {
        const int n = rowidx[amb[base + a]];
        v = *(const f32x4*)(x + (size_t)n * DIM + kk);
      }
      *(f32x4*)(&sx[a][kk]) = v;
    }
    __syncthreads();
    if (j >= V_VOCAB) continue;
    float s[ACH];
#pragma unroll
    for (int a = 0; a < ACH; ++a) s[a] = 0.f;
    for (int k = 0; k < DIM; ++k) {
      const float wv = W[(size_t)k * V_VOCAB + j];
#pragma unroll
      for (int a = 0; a < ACH; ++a) s[a] = fmaf(sx[a][k], wv, s[a]);
    }
#pragma unroll
    for (int a = 0; a < ACH; ++a) {
      if (base + a < namb) {
        const int tg = target[rowidx[amb[base + a]]];
        const float sc = s[a] + bj;
        const float st = sst[base + a];
        if (sc > st || (sc == st && j < tg)) atomicAdd(&rk[base + a], 1);
      }
    }
  }
}

// ---------------------------------------------------------------------------
// 7c. fixup decide
// ---------------------------------------------------------------------------
__global__ void k_fixdec(const int* __restrict__ rk, Ctrl* __restrict__ ctrl) {
  const int a = blockIdx.x * 256 + threadIdx.x;
  if (a < ctrl->namb && rk[a] <= KTOP - 1) atomicAdd(&ctrl->hits, 1);
}

// ---------------------------------------------------------------------------
// 8. finalize
// ---------------------------------------------------------------------------
__global__ void k_final(const Ctrl* __restrict__ ctrl, float* __restrict__ out) {
  out[0] = (float)ctrl->hits / (float)ctrl->mc;
}

// ---------------------------------------------------------------------------
extern "C" void kernel_launch(void* const* d_in, const int* in_sizes, int n_in,
                              void* d_out, int out_size, void* d_ws, size_t ws_size,
                              hipStream_t stream) {
  const float* x      = (const float*)d_in[0];   // [8192, 512]
  const int*   target = (const int*)d_in[1];     // [8192]
  const int*   mask   = (const int*)d_in[2];     // [8192]
  const float* W      = (const float*)d_in[3];   // [512, 50257]
  const float* b      = (const float*)d_in[4];   // [50257]
  float* out = (float*)d_out;

  char* ws = (char*)d_ws;
  unsigned short* Wt     = (unsigned short*)(ws + OFF_WT);
  unsigned short* Xc     = (unsigned short*)(ws + OFF_XC);
  float*          bpad   = (float*)(ws + OFF_BPAD);
  int*            rowidx = (int*)(ws + OFF_ROWIDX);
  float*          that   = (float*)(ws + OFF_THAT);
  unsigned int*   counts = (unsigned int*)(ws + OFF_COUNTS);
  int*            amb    = (int*)(ws + OFF_AMB);
  Ctrl*           ctrl   = (Ctrl*)(ws + OFF_CTRL);
  int*            rk     = (int*)(ws + OFF_RK);
  float*          sst    = (float*)(ws + OFF_SST);

  // zero counts + amb + ctrl + rk (contiguous region)
  hipMemsetAsync(ws + OFF_COUNTS, 0, 32768 + 32768 + 16 + 32768, stream);

  k_prep   <<<197, 256, 0, stream>>>(mask, b, bpad, rowidx, ctrl);
  k_twt    <<<dim3(788, 8), 256, 0, stream>>>(W, Wt);
  k_xc     <<<2048, 256, 0, stream>>>(x, rowidx, ctrl, Xc);
  k_that   <<<2048, 256, 0, stream>>>(Xc, Wt, bpad, rowidx, target, ctrl, that);
  k_count  <<<dim3(NT_N, 32), 512, 0, stream>>>(Xc, Wt, bpad, that, ctrl, counts);
  k_decide <<<32, 256, 0, stream>>>(counts, ctrl, amb);
  k_fixt   <<<128, 64, 0, stream>>>(x, W, b, rowidx, target, amb, ctrl, sst);
  k_fixscan<<<197, 256, 0, stream>>>(x, W, b, rowidx, target, amb, sst, ctrl, rk);
  k_fixdec <<<32, 256, 0, stream>>>(rk, ctrl);
  k_final  <<<1, 1, 0, stream>>>(ctrl, out);
}